// Round 3
// baseline (133.526 us; speedup 1.0000x reference)
//
#include <hip/hip_runtime.h>
#include <math.h>

// ---------------------------------------------------------------------------
// Exp-domain tree machine, round 3:
//  - P1 = 1 - P0 (ey rows are distributions; ex1 = 1 - ex0) -> half the FMAs
//  - compare recurrence folded to per-(s,node) consts {A1,B1,C0,D}+E,
//    stored transposed [s][node] for coalesced lane loads
//  - phase-3 low-depth attn terms hoisted (depths 0..4 invariant across r)
//  - log-time value-halving shuffle reduction (16 shuffles vs 80)
// ---------------------------------------------------------------------------

// workspace layout (float offsets)
#define NWS_EYT  0        // ey_t[16][1020] : ey transposed [a][j]
#define NWS_Q4   16320    // q4[4][256][4]  : per (s,node): {A1,B1,C0,D}
#define NWS_E1   20416    // e1[4][256]     : per (s,node): E
#define NWS_EVP  21440    // evp[256][16]   : per k: {ev0[0..7], ev1[0..7]}
// total 25536 floats = 102144 B

#define TINY 1.8600378e-44f   // exp(-BOUND - lc - LOG2)

struct WPtrs {
  const float* sw[8];
  const float* dw[8];
  const float* cw[8];
  const float* vw;
};

__device__ __forceinline__ float sigmoidf_(float x) {
  return 1.0f / (1.0f + __expf(-x));
}

__global__ void tm_precompute(WPtrs p, float* __restrict__ ws) {
  int tid = blockIdx.x * blockDim.x + threadIdx.x;
  if (tid < 1020) {
    int jg = tid;
    int v = (jg >> 2) + 1;
    int depth = 31 - __clz(v);
    int nS = (1 << depth) * 4;                 // rows (n*SHUF) at this depth
    int jl = jg - 4 * ((1 << depth) - 1);      // local row within depth
    const float* sw = p.sw[depth];             // (2, nS, 4)
    float p0[4];
#pragma unroll
    for (int k = 0; k < 4; k++)
      p0[k] = sigmoidf_(sw[jl * 4 + k] - sw[nS * 4 + jl * 4 + k]);
#pragma unroll
    for (int a = 0; a < 16; a++) {
      float prod = 1.0f;
#pragma unroll
      for (int k = 0; k < 4; k++) {
        int bit = (a >> (3 - k)) & 1;          // k=0 is MSB
        prod *= bit ? p0[k] : (1.0f - p0[k]);
      }
      ws[NWS_EYT + a * 1020 + jg] = prod;      // transposed [a][j]
    }
    // fold dw/cw into recurrence constants
    const float* dw = p.dw[depth];             // (2, nS)
    float ed0 = sigmoidf_(dw[jl] - dw[nS + jl]);
    float ed1 = 1.0f - ed0;
    const float* cw = p.cw[depth];             // (2, 1, n, 4) flat (2, nS)
    float W0 = sigmoidf_(cw[jl] - cw[nS + jl]);
    float W1 = 1.0f - W0;
    float A  = ed0 - ed1;                      // X10 = A*P0 + ed1
    float C  = 2.0f * ed0;                     // X11 = C*(1-P0)
    float A1 = A * W1, B1 = ed1 * W1;
    float A0 = A * W0, B0 = ed1 * W0;
    float C0 = C * W0, C1 = C * W1;
    float D  = A0 - C1;                        // X10*W0 + X11*W1 = D*P0 + E
    float E  = B0 + C1;
    int ng = jg >> 2, s = jg & 3;
    float* q = ws + NWS_Q4 + (s * 256 + ng) * 4;
    q[0] = A1; q[1] = B1; q[2] = C0; q[3] = D;
    ws[NWS_E1 + s * 256 + ng] = E;
  } else if (tid >= 1024 && tid < 3072) {
    int e = tid - 1024;                        // e = k*8 + d
    int k = e >> 3, d = e & 7;
    float v0 = sigmoidf_(p.vw[e] - p.vw[2048 + e]);
    ws[NWS_EVP + k * 16 + d]     = v0;
    ws[NWS_EVP + k * 16 + 8 + d] = 1.0f - v0;
  }
}

// 8 batch elements per block of 256; each wave handles 2 batch elements,
// lane = node chunk (64-wide split of 255 nodes).
__global__ __launch_bounds__(256) void tm_main(
    const float* __restrict__ x0,
    const float* __restrict__ ws, float* __restrict__ out) {
  __shared__ float ex0s[8][16];
  __shared__ float a_lds[8][255][2];           // per-node (a1, a2), log domain

  const int t  = threadIdx.x;
  const int b0 = blockIdx.x * 8;

  // stage exp(x0) for this block's 8 batch rows (ex1 = 1 - ex0, not needed)
  if (t < 128) {
    int bl = t >> 4, a = t & 15;
    ex0s[bl][a] = __expf(x0[(b0 + bl) * 16 + a]);
  }
  __syncthreads();

  const int wb   = t >> 6;        // wave id: handles batch rows 2wb, 2wb+1
  const int lane = t & 63;
  const int bl0  = wb * 2, bl1 = bl0 + 1;

  float e0A[16], e0B[16];
#pragma unroll
  for (int a = 0; a < 16; a++) {
    e0A[a] = ex0s[bl0][a];
    e0B[a] = ex0s[bl1][a];
  }

  const float4* __restrict__ eyt4 = (const float4*)(ws + NWS_EYT);
  const float4* __restrict__ q4   = (const float4*)(ws + NWS_Q4);
  const float*  __restrict__ e1   = ws + NWS_E1;

  // phase 2: per-node compare_fwd recurrence in exp domain
#pragma unroll
  for (int r = 0; r < 4; r++) {
    int ng = lane + 64 * r;
    if (ng < 255) {
      float PA[4] = {0, 0, 0, 0};
      float PB[4] = {0, 0, 0, 0};
#pragma unroll
      for (int a = 0; a < 16; a++) {
        const float4 w = eyt4[a * 255 + ng];   // coalesced: lanes consecutive
        PA[0] = fmaf(w.x, e0A[a], PA[0]);  PB[0] = fmaf(w.x, e0B[a], PB[0]);
        PA[1] = fmaf(w.y, e0A[a], PA[1]);  PB[1] = fmaf(w.y, e0B[a], PB[1]);
        PA[2] = fmaf(w.z, e0A[a], PA[2]);  PB[2] = fmaf(w.z, e0B[a], PB[2]);
        PA[3] = fmaf(w.w, e0A[a], PA[3]);  PB[3] = fmaf(w.w, e0B[a], PB[3]);
      }
      float S1a = TINY, S2a = 1.0f, S3a = TINY;
      float S1b = TINY, S2b = 1.0f, S3b = TINY;
#pragma unroll
      for (int s = 0; s < 4; s++) {
        const float4 q = q4[s * 256 + ng];     // {A1,B1,C0,D}, coalesced
        const float  E = e1[s * 256 + ng];
        {
          float p = PA[s];
          S1a = fmaf(S2a, fmaf(q.x, p, q.y), S1a);      // += S2*X10*W1
          S3a = fmaf(S2a, fmaf(-q.z, p, q.z), S3a);     // += S2*X11*W0
          S2a *= fmaf(q.w, p, E);                       // *= X10*W0+X11*W1
        }
        {
          float p = PB[s];
          S1b = fmaf(S2b, fmaf(q.x, p, q.y), S1b);
          S3b = fmaf(S2b, fmaf(-q.z, p, q.z), S3b);
          S2b *= fmaf(q.w, p, E);
        }
      }
      a_lds[bl0][ng][0] = __logf(S1a + S2a);
      a_lds[bl0][ng][1] = __logf(S3a);
      a_lds[bl1][ng][0] = __logf(S1b + S2b);
      a_lds[bl1][ng][1] = __logf(S3b);
    }
  }
  __syncthreads();

  // phase 3: attn over 256 branches + final logsumexp against values
  const int bl    = t >> 5;
  const int chunk = t & 31;
  const float4* __restrict__ evp = (const float4*)(ws + NWS_EVP);

  // depths 0..4 depend only on chunk (k mod 32) -> hoist
  float base = 0.f;
#pragma unroll
  for (int i2 = 0; i2 < 5; i2++) {
    int node = ((1 << i2) - 1) + (chunk & ((1 << i2) - 1));
    int ch   = (chunk >> i2) & 1;
    base += a_lds[bl][node][ch];
  }

  float attn[8];
  float mx = -3.0e38f;
#pragma unroll
  for (int r = 0; r < 8; r++) {
    int k = chunk + 32 * r;
    float ssum = base;
#pragma unroll
    for (int i2 = 5; i2 < 8; i2++) {
      int node = ((1 << i2) - 1) + (k & ((1 << i2) - 1));
      int ch   = (k >> i2) & 1;
      ssum += a_lds[bl][node][ch];
    }
    attn[r] = ssum;
    mx = fmaxf(mx, ssum);
  }
#pragma unroll
  for (int off = 1; off < 32; off <<= 1)
    mx = fmaxf(mx, __shfl_xor(mx, off, 64));
  mx = fmaxf(mx, -1.0e30f);                    // guard if all -inf

  float acc[16];
#pragma unroll
  for (int q = 0; q < 16; q++) acc[q] = 0.f;
#pragma unroll
  for (int r = 0; r < 8; r++) {
    int k = chunk + 32 * r;
    float e = __expf(attn[r] - mx);
    float4 v0 = evp[k * 4 + 0];
    float4 v1 = evp[k * 4 + 1];
    float4 v2 = evp[k * 4 + 2];
    float4 v3 = evp[k * 4 + 3];
    acc[0]  = fmaf(e, v0.x, acc[0]);  acc[1]  = fmaf(e, v0.y, acc[1]);
    acc[2]  = fmaf(e, v0.z, acc[2]);  acc[3]  = fmaf(e, v0.w, acc[3]);
    acc[4]  = fmaf(e, v1.x, acc[4]);  acc[5]  = fmaf(e, v1.y, acc[5]);
    acc[6]  = fmaf(e, v1.z, acc[6]);  acc[7]  = fmaf(e, v1.w, acc[7]);
    acc[8]  = fmaf(e, v2.x, acc[8]);  acc[9]  = fmaf(e, v2.y, acc[9]);
    acc[10] = fmaf(e, v2.z, acc[10]); acc[11] = fmaf(e, v2.w, acc[11]);
    acc[12] = fmaf(e, v3.x, acc[12]); acc[13] = fmaf(e, v3.y, acc[13]);
    acc[14] = fmaf(e, v3.z, acc[14]); acc[15] = fmaf(e, v3.w, acc[15]);
  }

  // value-halving butterfly: 16 outputs over 32 lanes in 16 shuffles.
  // After each step, lane keeps half the outputs; final output index is
  // bit-reversed lane id: q = 8*c0 + 4*c1 + 2*c2 + c3.
#define VH_STEP(OFF, HALF)                                          \
  {                                                                 \
    const bool hi = (chunk & (OFF)) != 0;                           \
    _Pragma("unroll")                                               \
    for (int q = 0; q < (HALF); q++) {                              \
      float send = hi ? acc[q] : acc[q + (HALF)];                   \
      float got  = __shfl_xor(send, (OFF), 64);                     \
      acc[q] = (hi ? acc[q + (HALF)] : acc[q]) + got;               \
    }                                                               \
  }
  VH_STEP(1, 8)
  VH_STEP(2, 4)
  VH_STEP(4, 2)
  VH_STEP(8, 1)
  acc[0] += __shfl_xor(acc[0], 16, 64);
#undef VH_STEP

  if (chunk < 16) {
    int qo = ((chunk & 1) << 3) | ((chunk & 2) << 1) |
             ((chunk & 4) >> 1) | ((chunk & 8) >> 3);
    float val = mx + __logf(acc[0]);
    int b = b0 + bl;
    if (qo < 8) out[b * 8 + qo] = val;                    // y0
    else        out[8192 * 8 + b * 8 + (qo - 8)] = val;   // y1
  }
}

extern "C" void kernel_launch(void* const* d_in, const int* in_sizes, int n_in,
                              void* d_out, int out_size, void* d_ws, size_t ws_size,
                              hipStream_t stream) {
  WPtrs p;
  const float* x0 = (const float*)d_in[0];
  if (in_sizes[3] == 8) {        // interleaved dict order sw0,dw0,cw0,sw1,...
    for (int i = 0; i < 8; i++) {
      p.sw[i] = (const float*)d_in[2 + 3 * i];
      p.dw[i] = (const float*)d_in[3 + 3 * i];
      p.cw[i] = (const float*)d_in[4 + 3 * i];
    }
  } else {                       // grouped signature order
    for (int i = 0; i < 8; i++) {
      p.sw[i] = (const float*)d_in[2 + i];
      p.dw[i] = (const float*)d_in[10 + i];
      p.cw[i] = (const float*)d_in[18 + i];
    }
  }
  p.vw = (const float*)d_in[26];

  float* ws = (float*)d_ws;
  tm_precompute<<<12, 256, 0, stream>>>(p, ws);
  tm_main<<<1024, 256, 0, stream>>>(x0, ws, (float*)d_out);
}

// Round 4
// 115.982 us; speedup vs baseline: 1.1513x; 1.1513x over previous
//
#include <hip/hip_runtime.h>
#include <math.h>

// ---------------------------------------------------------------------------
// Exp-domain tree machine, round 4:
//  - thread = tree node: ey row + recurrence consts live in REGISTERS,
//    loaded once per block; batch rows (16/block) loop over them.
//    Global table traffic 330 MB -> 44 MB.
//  - exp(x0) broadcast from LDS (same-address = conflict-free), pipelined
//    one batch-pair ahead.
//  - phase 3: depths 0-4 hoisted, depths 5-7 from 7 preloaded float2s;
//    y1 = Stot - y0 (v1 = 1 - v0); value table in LDS, b128 conflict-free.
// ---------------------------------------------------------------------------

// workspace layout (float offsets)
#define NWS_EYT  0        // ey_t[16][1020] : ey transposed [a][j]
#define NWS_Q4   16320    // q4[4][256][4]  : per (s,node): {A1,B1,C0,D}
#define NWS_E1   20416    // e1[4][256]     : per (s,node): E
#define NWS_EVT  21440    // evt[2][256][4] : v0(k, d=4i+c) at [i][k][c]
// total 23488 floats = 93952 B

#define TINY 1.8600378e-44f   // exp(-BOUND - lc - LOG2)

struct WPtrs {
  const float* sw[8];
  const float* dw[8];
  const float* cw[8];
  const float* vw;
};

__device__ __forceinline__ float sigmoidf_(float x) {
  return 1.0f / (1.0f + __expf(-x));
}

__global__ void tm_precompute(WPtrs p, float* __restrict__ ws) {
  int tid = blockIdx.x * blockDim.x + threadIdx.x;
  if (tid < 1020) {
    int jg = tid;
    int v = (jg >> 2) + 1;
    int depth = 31 - __clz(v);
    int nS = (1 << depth) * 4;                 // rows (n*SHUF) at this depth
    int jl = jg - 4 * ((1 << depth) - 1);      // local row within depth
    const float* sw = p.sw[depth];             // (2, nS, 4)
    float p0[4];
#pragma unroll
    for (int k = 0; k < 4; k++)
      p0[k] = sigmoidf_(sw[jl * 4 + k] - sw[nS * 4 + jl * 4 + k]);
#pragma unroll
    for (int a = 0; a < 16; a++) {
      float prod = 1.0f;
#pragma unroll
      for (int k = 0; k < 4; k++) {
        int bit = (a >> (3 - k)) & 1;          // k=0 is MSB
        prod *= bit ? p0[k] : (1.0f - p0[k]);
      }
      ws[NWS_EYT + a * 1020 + jg] = prod;      // transposed [a][j]
    }
    // fold dw/cw into recurrence constants
    const float* dw = p.dw[depth];             // (2, nS)
    float ed0 = sigmoidf_(dw[jl] - dw[nS + jl]);
    float ed1 = 1.0f - ed0;
    const float* cw = p.cw[depth];             // (2, 1, n, 4) flat (2, nS)
    float W0 = sigmoidf_(cw[jl] - cw[nS + jl]);
    float W1 = 1.0f - W0;
    float A  = ed0 - ed1;                      // X10 = A*P0 + ed1
    float C  = 2.0f * ed0;                     // X11 = C*(1-P0)
    float A1 = A * W1, B1 = ed1 * W1;
    float A0 = A * W0, B0 = ed1 * W0;
    float C0 = C * W0, C1 = C * W1;
    float D  = A0 - C1;                        // X10*W0 + X11*W1 = D*P0 + E
    float E  = B0 + C1;
    int ng = jg >> 2, s = jg & 3;
    float* q = ws + NWS_Q4 + (s * 256 + ng) * 4;
    q[0] = A1; q[1] = B1; q[2] = C0; q[3] = D;
    ws[NWS_E1 + s * 256 + ng] = E;
  } else if (tid >= 1024 && tid < 3072) {
    int e = tid - 1024;                        // e = k*8 + d
    int k = e >> 3, d = e & 7;
    float v0 = sigmoidf_(p.vw[e] - p.vw[2048 + e]);
    ws[NWS_EVT + ((d >> 2) * 256 + k) * 4 + (d & 3)] = v0;
  }
}

// 16 batch rows per block of 256 threads; thread = tree node (255 active)
// in phase 2, 32-lane branch groups in phase 3.
__global__ __launch_bounds__(256) void tm_main(
    const float* __restrict__ x0,
    const float* __restrict__ ws, float* __restrict__ out) {
  __shared__ float  ex0s[256];        // [b][a] 16x16 exp(x0)
  __shared__ float2 a_lds[16 * 256];  // [b][node] = (a1, a2), log domain
  __shared__ float4 evt_s[512];       // [i][k] : v0(k, 4i..4i+3)

  const int t  = threadIdx.x;
  const int b0 = blockIdx.x * 16;

  // stage exp(x0) + value table
  ex0s[t] = __expf(x0[b0 * 16 + t]);
  {
    const float4* evt_g = (const float4*)(ws + NWS_EVT);
    evt_s[t]       = evt_g[t];
    evt_s[t + 256] = evt_g[t + 256];
  }

  // per-node tables -> registers (once per block)
  float4 ey[16];
  float4 q[4];
  float  E[4];
  {
    const int node = (t < 255) ? t : 0;
    const float4* eyt4 = (const float4*)(ws + NWS_EYT);
    const float4* q4   = (const float4*)(ws + NWS_Q4);
    const float*  e1   = ws + NWS_E1;
#pragma unroll
    for (int a = 0; a < 16; a++) ey[a] = eyt4[a * 255 + node];
#pragma unroll
    for (int s = 0; s < 4; s++) { q[s] = q4[s * 256 + node]; E[s] = e1[s * 256 + node]; }
  }
  __syncthreads();

  // phase 2: loop over batch rows in pairs, ex broadcast from LDS,
  // pipelined one pair ahead.
  if (t < 255) {
    const float4* exv = (const float4*)ex0s;
    float4 cxa[4], cxb[4], nxa[4], nxb[4];
#pragma unroll
    for (int i = 0; i < 4; i++) { cxa[i] = exv[i]; cxb[i] = exv[4 + i]; }
#pragma unroll
    for (int b = 0; b < 16; b += 2) {
      if (b + 2 < 16) {
#pragma unroll
        for (int i = 0; i < 4; i++) {
          nxa[i] = exv[(b + 2) * 4 + i];
          nxb[i] = exv[(b + 3) * 4 + i];
        }
      }
      float eA[16], eB[16];
#pragma unroll
      for (int i = 0; i < 4; i++) {
        ((float4*)eA)[i] = cxa[i];
        ((float4*)eB)[i] = cxb[i];
      }
      float PA[4] = {0, 0, 0, 0}, PB[4] = {0, 0, 0, 0};
#pragma unroll
      for (int a = 0; a < 16; a++) {
        PA[0] = fmaf(ey[a].x, eA[a], PA[0]);  PB[0] = fmaf(ey[a].x, eB[a], PB[0]);
        PA[1] = fmaf(ey[a].y, eA[a], PA[1]);  PB[1] = fmaf(ey[a].y, eB[a], PB[1]);
        PA[2] = fmaf(ey[a].z, eA[a], PA[2]);  PB[2] = fmaf(ey[a].z, eB[a], PB[2]);
        PA[3] = fmaf(ey[a].w, eA[a], PA[3]);  PB[3] = fmaf(ey[a].w, eB[a], PB[3]);
      }
      float S1a = TINY, S2a = 1.0f, S3a = TINY;
      float S1b = TINY, S2b = 1.0f, S3b = TINY;
#pragma unroll
      for (int s = 0; s < 4; s++) {
        {
          float pp = PA[s];
          S1a = fmaf(S2a, fmaf(q[s].x, pp, q[s].y), S1a);   // += S2*X10*W1
          S3a = fmaf(S2a, fmaf(-q[s].z, pp, q[s].z), S3a);  // += S2*X11*W0
          S2a *= fmaf(q[s].w, pp, E[s]);                    // *= X10*W0+X11*W1
        }
        {
          float pp = PB[s];
          S1b = fmaf(S2b, fmaf(q[s].x, pp, q[s].y), S1b);
          S3b = fmaf(S2b, fmaf(-q[s].z, pp, q[s].z), S3b);
          S2b *= fmaf(q[s].w, pp, E[s]);
        }
      }
      a_lds[b * 256 + t]       = make_float2(__logf(S1a + S2a), __logf(S3a));
      a_lds[(b + 1) * 256 + t] = make_float2(__logf(S1b + S2b), __logf(S3b));
#pragma unroll
      for (int i = 0; i < 4; i++) { cxa[i] = nxa[i]; cxb[i] = nxb[i]; }
    }
  }
  __syncthreads();

  // phase 3: 8 groups of 32 lanes; group g handles rows g and g+8.
  const int g     = t >> 5;
  const int chunk = t & 31;
#pragma unroll
  for (int rr = 0; rr < 2; rr++) {
    const int row = g + 8 * rr;
    const float2* arow = a_lds + row * 256;

    // depths 0..4: r-invariant (k = chunk + 32r keeps bits 0..4)
    float base = 0.f;
#pragma unroll
    for (int i2 = 0; i2 < 5; i2++) {
      int node = ((1 << i2) - 1) + (chunk & ((1 << i2) - 1));
      float2 v = arow[node];
      base += ((chunk >> i2) & 1) ? v.y : v.x;
    }
    // depth 5: node fixed, ch = r&1 ; depth 6: 2 nodes, ch=(r>>1)&1 ;
    // depth 7: 4 nodes, ch = r>>2
    float2 A5  = arow[31 + chunk];
    float2 A6a = arow[63 + chunk];
    float2 A6b = arow[95 + chunk];
    float2 A7[4];
#pragma unroll
    for (int j = 0; j < 4; j++) A7[j] = arow[127 + chunk + 32 * j];

    float attn[8];
    float mx = -3.0e38f;
#pragma unroll
    for (int r = 0; r < 8; r++) {
      float t5 = (r & 1) ? A5.y : A5.x;
      float2 a6 = (r & 1) ? A6b : A6a;
      float t6 = ((r >> 1) & 1) ? a6.y : a6.x;
      float2 a7 = A7[r & 3];
      float t7 = (r >> 2) ? a7.y : a7.x;
      float ssum = base + t5 + t6 + t7;
      attn[r] = ssum;
      mx = fmaxf(mx, ssum);
    }
#pragma unroll
    for (int off = 1; off < 32; off <<= 1)
      mx = fmaxf(mx, __shfl_xor(mx, off, 64));
    mx = fmaxf(mx, -1.0e30f);                  // guard if all -inf

    float acc[8] = {0, 0, 0, 0, 0, 0, 0, 0};
    float Stot = 0.f;
#pragma unroll
    for (int r = 0; r < 8; r++) {
      int k = chunk + 32 * r;
      float e = __expf(attn[r] - mx);
      Stot += e;
      float4 v0 = evt_s[k];
      float4 v1 = evt_s[256 + k];
      acc[0] = fmaf(e, v0.x, acc[0]);  acc[1] = fmaf(e, v0.y, acc[1]);
      acc[2] = fmaf(e, v0.z, acc[2]);  acc[3] = fmaf(e, v0.w, acc[3]);
      acc[4] = fmaf(e, v1.x, acc[4]);  acc[5] = fmaf(e, v1.y, acc[5]);
      acc[6] = fmaf(e, v1.z, acc[6]);  acc[7] = fmaf(e, v1.w, acc[7]);
    }

    // value-halving butterfly: 8 accs -> 1 per lane (d = 4c0+2c1+c2),
    // then full sums over remaining offsets.
#define VH_STEP(OFF, HALF)                                          \
    {                                                               \
      const bool hi = (chunk & (OFF)) != 0;                         \
      _Pragma("unroll")                                             \
      for (int qq = 0; qq < (HALF); qq++) {                         \
        float send = hi ? acc[qq] : acc[qq + (HALF)];               \
        float got  = __shfl_xor(send, (OFF), 64);                   \
        acc[qq] = (hi ? acc[qq + (HALF)] : acc[qq]) + got;          \
      }                                                             \
    }
    VH_STEP(1, 4)
    VH_STEP(2, 2)
    VH_STEP(4, 1)
#undef VH_STEP
    float a0 = acc[0];
    a0 += __shfl_xor(a0, 8, 64);
    a0 += __shfl_xor(a0, 16, 64);
#pragma unroll
    for (int off = 1; off < 32; off <<= 1)
      Stot += __shfl_xor(Stot, off, 64);

    const int d = ((chunk & 1) << 2) | (chunk & 2) | ((chunk >> 2) & 1);
    const int b = b0 + row;
    if (chunk < 8)
      out[b * 8 + d] = mx + __logf(a0);                       // y0
    else if (chunk < 16)
      out[65536 + b * 8 + d] = mx + __logf(Stot - a0);        // y1
  }
}

extern "C" void kernel_launch(void* const* d_in, const int* in_sizes, int n_in,
                              void* d_out, int out_size, void* d_ws, size_t ws_size,
                              hipStream_t stream) {
  WPtrs p;
  const float* x0 = (const float*)d_in[0];
  if (in_sizes[3] == 8) {        // interleaved dict order sw0,dw0,cw0,sw1,...
    for (int i = 0; i < 8; i++) {
      p.sw[i] = (const float*)d_in[2 + 3 * i];
      p.dw[i] = (const float*)d_in[3 + 3 * i];
      p.cw[i] = (const float*)d_in[4 + 3 * i];
    }
  } else {                       // grouped signature order
    for (int i = 0; i < 8; i++) {
      p.sw[i] = (const float*)d_in[2 + i];
      p.dw[i] = (const float*)d_in[10 + i];
      p.cw[i] = (const float*)d_in[18 + i];
    }
  }
  p.vw = (const float*)d_in[26];

  float* ws = (float*)d_ws;
  tm_precompute<<<12, 256, 0, stream>>>(p, ws);
  tm_main<<<512, 256, 0, stream>>>(x0, ws, (float*)d_out);
}